// Round 5
// baseline (572.391 us; speedup 1.0000x reference)
//
#include <hip/hip_runtime.h>

#define N_TOK 2048
#define HD    1024
#define FD    4096
#define NE    8

typedef __attribute__((ext_vector_type(8))) short short8;
typedef __attribute__((ext_vector_type(4))) float floatx4;

// ---------- helpers ----------
__device__ __forceinline__ unsigned short f2bf(float f) {
  unsigned int u = __float_as_uint(f);
  u += 0x7fffu + ((u >> 16) & 1u);   // RNE
  return (unsigned short)(u >> 16);
}

__device__ __forceinline__ unsigned int pack2bf(float a, float b) {
  return (unsigned int)f2bf(a) | ((unsigned int)f2bf(b) << 16);
}

__device__ __forceinline__ void gl2lds16(const unsigned short* g, unsigned short* l) {
  __builtin_amdgcn_global_load_lds(
      (const __attribute__((address_space(1))) unsigned int*)g,
      (__attribute__((address_space(3))) unsigned int*)l, 16, 0, 0);
}

__device__ __forceinline__ float gelu_tanh(float x) {
  float t = 0.7978845608028654f * x * (1.0f + 0.044715f * x * x);
  return 0.5f * x * (1.0f + tanhf(t));
}

__device__ __forceinline__ int poff_of(const int* __restrict__ cnt, int e) {
  int o = 0;
  for (int i = 0; i < e; ++i) o += (cnt[i] + 127) & ~127;
  return o;
}

// ---------- gating + x -> bf16 convert (x read once, used twice) ----------
__global__ void k_gate_cvt(const float* __restrict__ x, const float* __restrict__ wg,
                           float* __restrict__ p, unsigned short* __restrict__ xb) {
  int wave = threadIdx.x >> 6;
  int lane = threadIdx.x & 63;
  int n = blockIdx.x * 4 + wave;
  const float4* xr = (const float4*)(x + (size_t)n * HD);
  float4 xv[4];
  #pragma unroll
  for (int i = 0; i < 4; ++i) xv[i] = xr[lane + i * 64];
  // bf16 side-product
  unsigned short* xrow = xb + (size_t)n * HD;
  #pragma unroll
  for (int i = 0; i < 4; ++i) {
    uint2 w;
    w.x = pack2bf(xv[i].x, xv[i].y);
    w.y = pack2bf(xv[i].z, xv[i].w);
    *(uint2*)(xrow + 4 * (lane + 64 * i)) = w;
  }
  for (int e = 0; e < NE; ++e) {
    const float4* wr = (const float4*)(wg + (size_t)e * HD);
    float s = 0.f;
    #pragma unroll
    for (int i = 0; i < 4; ++i) {
      float4 w4 = wr[lane + i * 64];
      s += xv[i].x * w4.x + xv[i].y * w4.y + xv[i].z * w4.z + xv[i].w * w4.w;
    }
    for (int o = 32; o > 0; o >>= 1) s += __shfl_xor(s, o, 64);
    if (lane == 0) p[e * N_TOK + n] = s;
  }
}

// ---------- softmax over axis=0 ----------
__global__ void k_softmax(float* __restrict__ p) {
  int e = blockIdx.x;
  float* col = p + e * N_TOK;
  __shared__ float red[256];
  int t = threadIdx.x;
  float m = -1e30f;
  for (int i = t; i < N_TOK; i += 256) m = fmaxf(m, col[i]);
  red[t] = m; __syncthreads();
  for (int s = 128; s > 0; s >>= 1) { if (t < s) red[t] = fmaxf(red[t], red[t + s]); __syncthreads(); }
  m = red[0]; __syncthreads();
  float sum = 0.f;
  for (int i = t; i < N_TOK; i += 256) { float v = expf(col[i] - m); col[i] = v; sum += v; }
  red[t] = sum; __syncthreads();
  for (int s = 128; s > 0; s >>= 1) { if (t < s) red[t] += red[t + s]; __syncthreads(); }
  float inv = 1.0f / red[0];
  for (int i = t; i < N_TOK; i += 256) col[i] *= inv;
}

// ---------- routing ----------
__global__ void k_route(const int* __restrict__ mp, const float* __restrict__ p,
                        int* __restrict__ cnt, int* __restrict__ idxl,
                        int* __restrict__ tke, int* __restrict__ tks, float* __restrict__ tkw) {
  int n = blockIdx.x * 256 + threadIdx.x;
  if (n >= N_TOK) return;
  int m0 = mp[n * 2 + 0], m1 = mp[n * 2 + 1];
  if (m0 == m1) {
    int s = atomicAdd(&cnt[m0], 1);
    idxl[m0 * N_TOK + s] = n;
    tke[n * 2] = m0; tks[n * 2] = s; tkw[n * 2] = 1.0f;
    tke[n * 2 + 1] = m0; tks[n * 2 + 1] = s; tkw[n * 2 + 1] = 0.0f;
  } else {
    float p0 = p[m0 * N_TOK + n], p1 = p[m1 * N_TOK + n];
    float inv = 1.0f / (p0 + p1);
    int s0 = atomicAdd(&cnt[m0], 1);
    idxl[m0 * N_TOK + s0] = n;
    tke[n * 2] = m0; tks[n * 2] = s0; tkw[n * 2] = p0 * inv;
    int s1 = atomicAdd(&cnt[m1], 1);
    idxl[m1 * N_TOK + s1] = n;
    tke[n * 2 + 1] = m1; tks[n * 2 + 1] = s1; tkw[n * 2 + 1] = p1 * inv;
  }
}

// ============================================================================
// GEMM1: h[slot] = gelu(x[tok(slot)] @ W1[e] + b1[e]) ; K=1024, tile 64x128
// A: gathered bf16 rows from xb via per-lane global_load_lds (no gather pass)
// B: W1 fp32 read directly; transpose+convert in registers -> Bs (stride 36)
// ============================================================================
__global__ __launch_bounds__(256) void k_gemm1(
    const unsigned short* __restrict__ xb, const float* __restrict__ w1,
    const float* __restrict__ b1, const int* __restrict__ cnt,
    const int* __restrict__ idxl, unsigned short* __restrict__ h) {
  const int l = blockIdx.x;
  const int r = l & 7;
  const int m = (l >> 3) & 31;
  const int q = l >> 8;
  const int e = q >> 2;
  const int n = ((q & 3) << 3) | r;        // XCD swizzle: same (e,n) group same XCD

  const int c = cnt[e];
  const int mbase = m * 64;
  if (mbase >= c) return;
  const int nbase = n * 128;
  const int po = poff_of(cnt, e);

  __shared__ unsigned short As[64 * 32];     // row-major, stride 32
  __shared__ unsigned short Bs[128 * 36];    // row n, stride 36 shorts (bank-spread)

  const int tid = threadIdx.x;
  const int wave = tid >> 6, lane = tid & 63;
  const int quad = lane >> 4, lrow = lane & 15;
  const int wn = wave * 32;

  // A staging: thread -> (row rA, k-chunk kA); gathered token row resolved once
  const int rA = tid >> 2, kA = (tid & 3) * 8;
  const int tokA = idxl[e * N_TOK + min(mbase + rA, c - 1)];
  const unsigned short* gArow = xb + (size_t)tokA * HD + kA;

  // B staging: thread -> k-quad kg (k0=4*kg), n-quad nc (n0=4*nc)
  const int kg = tid & 7, nc = tid >> 3;
  const int k0 = kg * 4, n0 = nc * 4;
  const float* gB = w1 + ((size_t)e * HD) * FD + (size_t)k0 * FD + nbase + n0;

  floatx4 acc[4][2];
  #pragma unroll
  for (int i = 0; i < 4; ++i)
    #pragma unroll
    for (int j = 0; j < 2; ++j) acc[i][j] = (floatx4){0.f, 0.f, 0.f, 0.f};

  for (int kt = 0; kt < HD / 32; ++kt) {
    __syncthreads();
    // A: async gather (per-lane global address, sequential LDS slots)
    gl2lds16(gArow + kt * 32, As + (size_t)(wave * 64) * 8);
    // B: fp32 load + transpose/convert
    float4 wv[4];
    const float* gBk = gB + (size_t)kt * 32 * FD;
    #pragma unroll
    for (int rr = 0; rr < 4; ++rr) wv[rr] = *(const float4*)(gBk + (size_t)rr * FD);
    #pragma unroll
    for (int i = 0; i < 4; ++i) {
      float v0 = (&wv[0].x)[i], v1 = (&wv[1].x)[i], v2 = (&wv[2].x)[i], v3 = (&wv[3].x)[i];
      uint2 wpk; wpk.x = pack2bf(v0, v1); wpk.y = pack2bf(v2, v3);
      *(uint2*)(Bs + (n0 + i) * 36 + k0) = wpk;
    }
    __syncthreads();
    short8 aF[4], bF[2];
    #pragma unroll
    for (int i = 0; i < 4; ++i) aF[i] = *(const short8*)(As + (i * 16 + lrow) * 32 + quad * 8);
    #pragma unroll
    for (int j = 0; j < 2; ++j) {
      union { short8 v; uint2 u[2]; } bb;
      const uint2* bp = (const uint2*)(Bs + (wn + j * 16 + lrow) * 36 + quad * 8);
      bb.u[0] = bp[0]; bb.u[1] = bp[1];
      bF[j] = bb.v;
    }
    #pragma unroll
    for (int i = 0; i < 4; ++i)
      #pragma unroll
      for (int j = 0; j < 2; ++j)
        acc[i][j] = __builtin_amdgcn_mfma_f32_16x16x32_bf16(aF[i], bF[j], acc[i][j], 0, 0, 0);
  }

  const size_t hrow0 = (size_t)po + mbase;
  #pragma unroll
  for (int i = 0; i < 4; ++i) {
    #pragma unroll
    for (int rr = 0; rr < 4; ++rr) {
      int row = i * 16 + quad * 4 + rr;
      unsigned short* hr = h + (hrow0 + row) * FD + nbase;
      #pragma unroll
      for (int j = 0; j < 2; ++j) {
        int col = wn + j * 16 + lrow;
        float v = acc[i][j][rr] + b1[e * FD + nbase + col];
        hr[col] = f2bf(gelu_tanh(v));
      }
    }
  }
}

// ============================================================================
// GEMM2: ya = h @ W2[e] ; K=4096, tile 64x128 over global padded rows
// A: h bf16 direct (global_load_lds); B: W2 fp32 transpose-staged
// swizzle: l = n + 8*m -> same-(n) blocks share an XCD (W2 n-slice L2-resident)
// ============================================================================
__global__ __launch_bounds__(256) void k_gemm2(
    const unsigned short* __restrict__ h, const float* __restrict__ w2,
    const int* __restrict__ cnt, unsigned short* __restrict__ ya) {
  const int l = blockIdx.x;
  const int n = l & 7;
  const int mt = l >> 3;
  const int mbase = mt * 64;
  const int nbase = n * 128;

  // expert lookup over padded row space
  int e = -1, po = 0, ce = 0;
  {
    int o = 0;
    #pragma unroll
    for (int i = 0; i < NE; ++i) {
      int ci = cnt[i];
      int pc = (ci + 127) & ~127;
      if (mbase >= o && mbase < o + pc) { e = i; po = o; ce = ci; }
      o += pc;
    }
  }
  if (e < 0) return;
  if (mbase - po >= ce) return;

  __shared__ unsigned short As[64 * 32];
  __shared__ unsigned short Bs[128 * 36];

  const int tid = threadIdx.x;
  const int wave = tid >> 6, lane = tid & 63;
  const int quad = lane >> 4, lrow = lane & 15;
  const int wn = wave * 32;

  const int rA = tid >> 2, kA = (tid & 3) * 8;
  const unsigned short* gArow = h + (size_t)(mbase + rA) * FD + kA;

  const int kg = tid & 7, nc = tid >> 3;
  const int k0 = kg * 4, n0 = nc * 4;
  const float* gB = w2 + ((size_t)e * FD) * HD + (size_t)k0 * HD + nbase + n0;

  floatx4 acc[4][2];
  #pragma unroll
  for (int i = 0; i < 4; ++i)
    #pragma unroll
    for (int j = 0; j < 2; ++j) acc[i][j] = (floatx4){0.f, 0.f, 0.f, 0.f};

  for (int kt = 0; kt < FD / 32; ++kt) {
    __syncthreads();
    gl2lds16(gArow + kt * 32, As + (size_t)(wave * 64) * 8);
    float4 wv[4];
    const float* gBk = gB + (size_t)kt * 32 * HD;
    #pragma unroll
    for (int rr = 0; rr < 4; ++rr) wv[rr] = *(const float4*)(gBk + (size_t)rr * HD);
    #pragma unroll
    for (int i = 0; i < 4; ++i) {
      float v0 = (&wv[0].x)[i], v1 = (&wv[1].x)[i], v2 = (&wv[2].x)[i], v3 = (&wv[3].x)[i];
      uint2 wpk; wpk.x = pack2bf(v0, v1); wpk.y = pack2bf(v2, v3);
      *(uint2*)(Bs + (n0 + i) * 36 + k0) = wpk;
    }
    __syncthreads();
    short8 aF[4], bF[2];
    #pragma unroll
    for (int i = 0; i < 4; ++i) aF[i] = *(const short8*)(As + (i * 16 + lrow) * 32 + quad * 8);
    #pragma unroll
    for (int j = 0; j < 2; ++j) {
      union { short8 v; uint2 u[2]; } bb;
      const uint2* bp = (const uint2*)(Bs + (wn + j * 16 + lrow) * 36 + quad * 8);
      bb.u[0] = bp[0]; bb.u[1] = bp[1];
      bF[j] = bb.v;
    }
    #pragma unroll
    for (int i = 0; i < 4; ++i)
      #pragma unroll
      for (int j = 0; j < 2; ++j)
        acc[i][j] = __builtin_amdgcn_mfma_f32_16x16x32_bf16(aF[i], bF[j], acc[i][j], 0, 0, 0);
  }

  #pragma unroll
  for (int i = 0; i < 4; ++i) {
    #pragma unroll
    for (int rr = 0; rr < 4; ++rr) {
      int row = mbase + i * 16 + quad * 4 + rr;
      unsigned short* yr = ya + (size_t)row * HD + nbase;
      #pragma unroll
      for (int j = 0; j < 2; ++j) {
        int col = wn + j * 16 + lrow;
        yr[col] = f2bf(acc[i][j][rr]);
      }
    }
  }
}

// ---------- combine: out[n] = sum_k w_k * (ya[pos_k] + b2[e_k]) ----------
__global__ __launch_bounds__(256) void k_combine(
    const unsigned short* __restrict__ ya, const float* __restrict__ b2,
    const int* __restrict__ cnt, const int* __restrict__ tke,
    const int* __restrict__ tks, const float* __restrict__ tkw,
    float* __restrict__ out) {
  int n = blockIdx.x;
  int e0 = tke[n * 2], e1 = tke[n * 2 + 1];
  int p0 = poff_of(cnt, e0) + tks[n * 2];
  int p1 = poff_of(cnt, e1) + tks[n * 2 + 1];
  float w0 = tkw[n * 2], w1 = tkw[n * 2 + 1];
  int c = threadIdx.x * 4;
  union { unsigned short us[4]; unsigned long long ll; } y0, y1;
  y0.ll = *(const unsigned long long*)(ya + (size_t)p0 * HD + c);
  y1.ll = *(const unsigned long long*)(ya + (size_t)p1 * HD + c);
  float4 bb0 = *(const float4*)(b2 + (size_t)e0 * HD + c);
  float4 bb1 = *(const float4*)(b2 + (size_t)e1 * HD + c);
  float4 o;
  o.x = w0 * (__uint_as_float((unsigned)y0.us[0] << 16) + bb0.x) + w1 * (__uint_as_float((unsigned)y1.us[0] << 16) + bb1.x);
  o.y = w0 * (__uint_as_float((unsigned)y0.us[1] << 16) + bb0.y) + w1 * (__uint_as_float((unsigned)y1.us[1] << 16) + bb1.y);
  o.z = w0 * (__uint_as_float((unsigned)y0.us[2] << 16) + bb0.z) + w1 * (__uint_as_float((unsigned)y1.us[2] << 16) + bb1.z);
  o.w = w0 * (__uint_as_float((unsigned)y0.us[3] << 16) + bb0.w) + w1 * (__uint_as_float((unsigned)y1.us[3] << 16) + bb1.w);
  *(float4*)(out + (size_t)n * HD + c) = o;
}

// ---------- launch ----------
extern "C" void kernel_launch(void* const* d_in, const int* in_sizes, int n_in,
                              void* d_out, int out_size, void* d_ws, size_t ws_size,
                              hipStream_t stream) {
  const float* x  = (const float*)d_in[0];
  const int*   mp = (const int*)d_in[1];
  const float* wg = (const float*)d_in[2];
  const float* w1 = (const float*)d_in[3];
  const float* b1 = (const float*)d_in[4];
  const float* w2 = (const float*)d_in[5];
  const float* b2 = (const float*)d_in[6];
  float* out = (float*)d_out;
  char* ws = (char*)d_ws;

  float* p    = (float*)(ws + 0);            // 65536
  int*   cnt  = (int*)(ws + 65536);          // 32
  int*   idxl = (int*)(ws + 66048);          // 65536
  int*   tke  = (int*)(ws + 131584);         // 16384
  int*   tks  = (int*)(ws + 147968);         // 16384
  float* tkw  = (float*)(ws + 164352);       // 16384
  size_t off = 180736;
  unsigned short* xb = (unsigned short*)(ws + off);  off += (size_t)N_TOK * HD * 2;    // 4 MB
  unsigned short* h  = (unsigned short*)(ws + off);  off += (size_t)5120 * FD * 2;     // 40 MB
  unsigned short* ya = (unsigned short*)(ws + off);  off += (size_t)5120 * HD * 2;     // 10 MB

  hipMemsetAsync(cnt, 0, 32, stream);

  k_gate_cvt<<<512, 256, 0, stream>>>(x, wg, p, xb);
  k_softmax<<<NE, 256, 0, stream>>>(p);
  k_route<<<NE, 256, 0, stream>>>(mp, p, cnt, idxl, tke, tks, tkw);
  k_gemm1<<<8192, 256, 0, stream>>>(xb, w1, b1, cnt, idxl, h);
  k_gemm2<<<80 * 8, 256, 0, stream>>>(h, w2, cnt, ya);
  k_combine<<<N_TOK, 256, 0, stream>>>(ya, b2, cnt, tke, tks, tkw, out);
}